// Round 1
// baseline (344.211 us; speedup 1.0000x reference)
//
#include <hip/hip_runtime.h>

// Problem constants (from reference setup_inputs)
#define BATCH    1024
#define SEQ      4096
#define FEAT     11
#define FACTOR   (-1.0f)

#define NTHREADS 256
#define TS       1024                    // timesteps per tile
#define NT       (SEQ / TS)              // 4 tiles
#define CPT      (TS / NTHREADS)         // 4 timesteps per thread
#define FPT      (CPT * FEAT)            // 44 floats per thread
#define TILE_FLOATS (TS * FEAT)          // 11264
#define TILE_F4  (TILE_FLOATS / 4)       // 2816 float4 per tile
#define VL       (TILE_F4 / NTHREADS)    // 11 float4 loads per thread

__global__ __launch_bounds__(NTHREADS)
void rnn_scan_kernel(const float* __restrict__ x,
                     const float* __restrict__ init_state,
                     float* __restrict__ y) {
    __shared__ float4 tile_lds[TILE_F4];     // 45,056 B
    __shared__ float  waveTot[4][FEAT];      // 176 B

    const int b    = blockIdx.x;
    const int t    = threadIdx.x;
    const int lane = t & 63;
    const int wav  = t >> 6;

    const float4* __restrict__ xg =
        (const float4*)(x + (size_t)b * (SEQ * FEAT));
    float4* __restrict__ yg =
        (float4*)(y + (size_t)b * (SEQ * FEAT));
    const float init_v = init_state[b];

    float carry[FEAT];
#pragma unroll
    for (int f = 0; f < FEAT; ++f) carry[f] = 0.0f;

    // Prologue: load tile 0
    float4 cur[VL];
#pragma unroll
    for (int i = 0; i < VL; ++i) cur[i] = xg[t + NTHREADS * i];

#pragma unroll
    for (int tile = 0; tile < NT; ++tile) {
        // ---- Phase A: stage x tile to LDS (linear float4 layout) ----
#pragma unroll
        for (int i = 0; i < VL; ++i) tile_lds[t + NTHREADS * i] = cur[i];
        __syncthreads();

        // Prefetch next tile's globals (latency hidden under phases B-D)
        if (tile + 1 < NT) {
#pragma unroll
            for (int i = 0; i < VL; ++i)
                cur[i] = xg[(tile + 1) * TILE_F4 + t + NTHREADS * i];
        }

        // ---- Phase B: own 4 consecutive timesteps (44 floats) ----
        float v[FPT];
#pragma unroll
        for (int k = 0; k < VL; ++k) {
            float4 q = tile_lds[VL * t + k];   // 11t+k: coprime w/ bankgroups
            v[4 * k + 0] = q.x; v[4 * k + 1] = q.y;
            v[4 * k + 2] = q.z; v[4 * k + 3] = q.w;
        }
        // local inclusive prefix over the 4 timesteps, per feature
#pragma unroll
        for (int s = 1; s < CPT; ++s)
#pragma unroll
            for (int f = 0; f < FEAT; ++f)
                v[s * FEAT + f] += v[(s - 1) * FEAT + f];

        // wave-level inclusive scan of per-thread totals
        float inc[FEAT];
#pragma unroll
        for (int f = 0; f < FEAT; ++f) inc[f] = v[(CPT - 1) * FEAT + f];
#pragma unroll
        for (int d = 1; d < 64; d <<= 1) {
#pragma unroll
            for (int f = 0; f < FEAT; ++f) {
                float o = __shfl_up(inc[f], d, 64);
                if (lane >= d) inc[f] += o;
            }
        }
        if (lane == 63) {
#pragma unroll
            for (int f = 0; f < FEAT; ++f) waveTot[wav][f] = inc[f];
        }
        __syncthreads();

        // ---- Phase C: offsets + epilogue math, write y to own LDS slots ----
        float base[FEAT];
#pragma unroll
        for (int f = 0; f < FEAT; ++f) {
            float off = carry[f] + inc[f] - v[(CPT - 1) * FEAT + f]; // excl in wave
#pragma unroll
            for (int w = 0; w < 4; ++w) {
                float wt = waveTot[w][f];
                if (w < wav) off += wt;   // preceding waves
                carry[f] += wt;           // full-tile total -> next tile carry
            }
            base[f] = off;
        }
#pragma unroll
        for (int s = 0; s < CPT; ++s)
#pragma unroll
            for (int f = 0; f < FEAT; ++f)
                v[s * FEAT + f] = init_v + FACTOR * (base[f] + v[s * FEAT + f]);
#pragma unroll
        for (int k = 0; k < VL; ++k) {
            float4 q;
            q.x = v[4 * k + 0]; q.y = v[4 * k + 1];
            q.z = v[4 * k + 2]; q.w = v[4 * k + 3];
            tile_lds[VL * t + k] = q;
        }
        __syncthreads();

        // ---- Phase D: coalesced float4 store ----
        // (reads own slots t+256i; next tile's Phase A rewrites the same
        //  slots from the same thread -> no 4th barrier needed)
#pragma unroll
        for (int i = 0; i < VL; ++i)
            yg[tile * TILE_F4 + t + NTHREADS * i] = tile_lds[t + NTHREADS * i];
    }
}

extern "C" void kernel_launch(void* const* d_in, const int* in_sizes, int n_in,
                              void* d_out, int out_size, void* d_ws, size_t ws_size,
                              hipStream_t stream) {
    const float* x    = (const float*)d_in[0];
    const float* init = (const float*)d_in[1];
    float*       y    = (float*)d_out;
    rnn_scan_kernel<<<dim3(BATCH), dim3(NTHREADS), 0, stream>>>(x, init, y);
}